// Round 3
// baseline (60.355 us; speedup 1.0000x reference)
//
#include <hip/hip_runtime.h>
#include <math.h>

#define NB 512
#define NK 64
#define NP 25
#define HW 400
#define NC 10
#define NWAVE 8

// Compute 10 pixels of one output row. WOFF = window-relative col offset
// (0 for col-half 0, 2 for col-half 1) kept compile-time so Wf/patv indexing
// is static (runtime-indexed register arrays spill to scratch).
template<int WOFF>
__device__ __forceinline__ void row10(const float (&Wf)[5][16], const float (&patv)[NP],
                                      int sbase, float& smin, int& bi)
{
    #pragma unroll
    for (int px = 0; px < 10; ++px) {
        float s = 0.f;
        #pragma unroll
        for (int dy = 0; dy < 5; ++dy)
            #pragma unroll
            for (int dx = 0; dx < 5; ++dx)
                s += fabsf(patv[dy * 5 + dx] - Wf[dy][WOFF + px + dx]);
        const int p = sbase + px;
        if (s < smin) { smin = s; bi = p; }   // strict <: first occurrence
    }
}

__global__ __launch_bounds__(512, 4) void geneo_mlp_kernel(
    const float* __restrict__ x,        // (B,1,20,20)
    const float* __restrict__ patterns, // (K,1,5,5)
    const float* __restrict__ w2,       // (1,K)
    const float* __restrict__ b2,       // (1,)
    const float* __restrict__ wf,       // (NC,400)
    const float* __restrict__ bf,       // (NC,)
    float* __restrict__ out)            // (B,NC)
{
    __shared__ __align__(16) float xp[24 * 24];
    __shared__ float  redv[NWAVE][NK];
    __shared__ int    redi[NWAVE][NK];
    __shared__ float2 contrib[NK];      // (F*w2, bitcast idx)
    __shared__ float  wsum[NWAVE][NC];

    const int tid  = threadIdx.x;
    const int b    = blockIdx.x;
    const int lane = tid & 63;
    const int wave = tid >> 6;
    const int rw   = wave >> 1;   // row block: rows rw*5 .. rw*5+4
    const int ch   = wave & 1;    // col half:  cols ch*10 .. ch*10+9

    // ---- stage padded image (pad=2, 24x24, row stride 96B = 16B-aligned) ----
    for (int i = tid; i < 24 * 24; i += 512) {
        const int h = i / 24, w = i % 24;
        float v = 0.f;
        if (h >= 2 && h < 22 && w >= 2 && w < 22)
            v = x[b * HW + (h - 2) * 20 + (w - 2)];
        xp[i] = v;
    }

    // ---- lane owns pattern k = lane: 25 values in registers ----
    float patv[NP];
    #pragma unroll
    for (int j = 0; j < NP; ++j) patv[j] = patterns[lane * NP + j];
    __syncthreads();

    // ---- per-wave: 5 rows x 10 cols, all 64 k in parallel (lane = k) ----
    float smin = 1e30f;
    int   bi   = 0;

    #pragma unroll 1
    for (int r = 0; r < 5; ++r) {
        const int h = rw * 5 + r;

        // full window: 5 input rows x 16 cols from aligned base col ch*8
        // (ch=0 needs cols 0..13, ch=1 needs 10..23 -> window 8..23)
        float Wf[5][16];
        #pragma unroll
        for (int q = 0; q < 5; ++q) {
            const float* rp = &xp[(h + q) * 24 + ch * 8];
            const float4 a = *reinterpret_cast<const float4*>(rp + 0);
            const float4 c = *reinterpret_cast<const float4*>(rp + 4);
            const float4 d = *reinterpret_cast<const float4*>(rp + 8);
            const float4 e = *reinterpret_cast<const float4*>(rp + 12);
            Wf[q][0]  = a.x; Wf[q][1]  = a.y; Wf[q][2]  = a.z; Wf[q][3]  = a.w;
            Wf[q][4]  = c.x; Wf[q][5]  = c.y; Wf[q][6]  = c.z; Wf[q][7]  = c.w;
            Wf[q][8]  = d.x; Wf[q][9]  = d.y; Wf[q][10] = d.z; Wf[q][11] = d.w;
            Wf[q][12] = e.x; Wf[q][13] = e.y; Wf[q][14] = e.z; Wf[q][15] = e.w;
        }
        const int sbase = h * 20 + ch * 10;
        if (ch == 0) row10<0>(Wf, patv, sbase, smin, bi);
        else         row10<2>(Wf, patv, sbase, smin, bi);
    }
    redv[wave][lane] = smin;
    redi[wave][lane] = bi;
    __syncthreads();

    // ---- combine 8 wave partials per k, lexicographic (smin, idx) min ----
    if (tid < NK) {
        float v0 = redv[0][tid];
        int   i0 = redi[0][tid];
        #pragma unroll
        for (int w = 1; w < NWAVE; ++w) {
            const float ov = redv[w][tid];
            const int   oi = redi[w][tid];
            if (ov < v0 || (ov == v0 && oi < i0)) { v0 = ov; i0 = oi; }
        }
        const float F = 1.f - v0 * (1.f / 25.f);
        contrib[tid] = make_float2(F * w2[tid], __int_as_float(i0));
    }
    __syncthreads();

    // ---- sigmoid(scatter + b2) at owned pixel; partial 400->10 dot ----
    float acc[NC];
    #pragma unroll
    for (int c = 0; c < NC; ++c) acc[c] = 0.f;

    if (tid < HW) {
        float s = b2[0];
        for (int k = 0; k < NK; ++k) {
            const float2 cv = contrib[k];
            if (__float_as_int(cv.y) == tid) s += cv.x;
        }
        const float t = 1.f / (1.f + expf(-s));
        #pragma unroll
        for (int c = 0; c < NC; ++c) acc[c] += t * wf[c * HW + tid];
    }

    // ---- block-reduce the 10 class sums across 8 waves ----
    #pragma unroll
    for (int c = 0; c < NC; ++c) {
        #pragma unroll
        for (int off = 32; off >= 1; off >>= 1)
            acc[c] += __shfl_down(acc[c], off);
    }
    if (lane == 0) {
        #pragma unroll
        for (int c = 0; c < NC; ++c) wsum[wave][c] = acc[c];
    }
    __syncthreads();
    if (tid < NC) {
        float s = bf[tid];
        #pragma unroll
        for (int w = 0; w < NWAVE; ++w) s += wsum[w][tid];
        out[b * NC + tid] = 1.f / (1.f + expf(-s));
    }
}

extern "C" void kernel_launch(void* const* d_in, const int* in_sizes, int n_in,
                              void* d_out, int out_size, void* d_ws, size_t ws_size,
                              hipStream_t stream) {
    const float* x        = (const float*)d_in[0];
    const float* patterns = (const float*)d_in[1];
    const float* w2       = (const float*)d_in[2];
    const float* b2       = (const float*)d_in[3];
    const float* wf       = (const float*)d_in[4];
    const float* bf       = (const float*)d_in[5];
    float* out = (float*)d_out;

    geneo_mlp_kernel<<<NB, 512, 0, stream>>>(x, patterns, w2, b2, wf, bf, out);
}

// Round 4
// 23.888 us; speedup vs baseline: 2.5265x; 2.5265x over previous
//
#include <hip/hip_runtime.h>
#include <math.h>

#define NB 512
#define NK 64
#define NP 25
#define HW 400
#define NC 10
#define NWAVE 8

__global__ __launch_bounds__(512) void geneo_mlp_kernel(
    const float* __restrict__ x,        // (B,1,20,20)
    const float* __restrict__ patterns, // (K,1,5,5)
    const float* __restrict__ w2,       // (1,K)
    const float* __restrict__ b2,       // (1,)
    const float* __restrict__ wf,       // (NC,400)
    const float* __restrict__ bf,       // (NC,)
    float* __restrict__ out)            // (B,NC)
{
    // 4 pre-shifted copies of the padded 24x24 image: copy j holds
    // padded col (w + j) at index w, so strip cs reads 16B-aligned at
    // base col cs*4 of copy cs (orig cols cs*5 .. cs*5+8).
    __shared__ __align__(16) float xps[4][24 * 24];
    __shared__ float  redv[NWAVE][NK];
    __shared__ int    redi[NWAVE][NK];
    __shared__ float2 contrib[NK];      // (F*w2, bitcast idx)
    __shared__ float  wsum[NWAVE][NC];

    const int tid  = threadIdx.x;
    const int b    = blockIdx.x;
    const int lane = tid & 63;
    const int wave = tid >> 6;
    const int rw   = wave >> 2;   // row half:  rows rw*10 .. rw*10+9
    const int cs   = wave & 3;    // col strip: cols cs*5 .. cs*5+4

    // ---- stage 4 shifted padded copies (pad=2; outside -> 0) ----
    for (int i = tid; i < 4 * 576; i += 512) {
        const int cp  = i / 576;
        const int rem = i - cp * 576;
        const int ph  = rem / 24;         // padded row
        const int w0  = rem - ph * 24;    // index within copy
        const int pc  = w0 + cp;          // original padded col
        float v = 0.f;
        if (ph >= 2 && ph < 22 && pc >= 2 && pc < 22)
            v = x[b * HW + (ph - 2) * 20 + (pc - 2)];
        xps[cp][ph * 24 + w0] = v;
    }

    // ---- lane owns pattern k = lane: 25 values in registers ----
    float patv[NP];
    #pragma unroll
    for (int j = 0; j < NP; ++j) patv[j] = patterns[lane * NP + j];
    __syncthreads();

    // ---- strip: 10 rows x 5 cols, all 64 k in parallel (lane = k) ----
    const float* xbase = &xps[cs][cs * 4];   // row r at xbase + r*24, cols 0..8 used
    const int H0    = rw * 10;
    const int col0  = cs * 5;

    float smin = 1e30f;
    int   bi   = 0;
    float Wf[5][9];                          // 45 VGPRs, static-indexed only

    // initial fill: padded rows H0..H0+4 -> slots 0..4
    #pragma unroll
    for (int q = 0; q < 5; ++q) {
        const float* rp = xbase + (H0 + q) * 24;
        const float4 a = *reinterpret_cast<const float4*>(rp);
        const float4 c = *reinterpret_cast<const float4*>(rp + 4);
        Wf[q][0] = a.x; Wf[q][1] = a.y; Wf[q][2] = a.z; Wf[q][3] = a.w;
        Wf[q][4] = c.x; Wf[q][5] = c.y; Wf[q][6] = c.z; Wf[q][7] = c.w;
        Wf[q][8] = rp[8];
    }

    #pragma unroll 1
    for (int rr = 0; rr < 2; ++rr) {
        #pragma unroll
        for (int p = 0; p < 5; ++p) {        // phase: slot indices static
            const int i = rr * 5 + p;        // step 0..9
            const int h = H0 + i;            // output row
            #pragma unroll
            for (int px = 0; px < 5; ++px) {
                float s = 0.f;
                #pragma unroll
                for (int dy = 0; dy < 5; ++dy) {
                    const int slot = (p + dy) % 5;   // compile-time
                    #pragma unroll
                    for (int dx = 0; dx < 5; ++dx)
                        s += fabsf(patv[dy * 5 + dx] - Wf[slot][px + dx]);
                }
                const int pix = h * 20 + col0 + px;
                if (s < smin) { smin = s; bi = pix; }   // strict <: first occ.
            }
            // retire slot p, load padded row h+5 (exists while i < 9)
            if (rr * 5 + p < 9) {
                const float* rp = xbase + (h + 5) * 24;
                const float4 a = *reinterpret_cast<const float4*>(rp);
                const float4 c = *reinterpret_cast<const float4*>(rp + 4);
                Wf[p][0] = a.x; Wf[p][1] = a.y; Wf[p][2] = a.z; Wf[p][3] = a.w;
                Wf[p][4] = c.x; Wf[p][5] = c.y; Wf[p][6] = c.z; Wf[p][7] = c.w;
                Wf[p][8] = rp[8];
            }
        }
    }
    redv[wave][lane] = smin;
    redi[wave][lane] = bi;
    __syncthreads();

    // ---- combine 8 wave partials per k, lexicographic (s, idx) min ----
    if (tid < NK) {
        float v0 = redv[0][tid];
        int   i0 = redi[0][tid];
        #pragma unroll
        for (int w = 1; w < NWAVE; ++w) {
            const float ov = redv[w][tid];
            const int   oi = redi[w][tid];
            if (ov < v0 || (ov == v0 && oi < i0)) { v0 = ov; i0 = oi; }
        }
        const float F = 1.f - v0 * (1.f / 25.f);
        contrib[tid] = make_float2(F * w2[tid], __int_as_float(i0));
    }
    __syncthreads();

    // ---- sigmoid(scatter + b2) at owned pixel; partial 400->10 dot ----
    float acc[NC];
    #pragma unroll
    for (int c = 0; c < NC; ++c) acc[c] = 0.f;

    if (tid < HW) {
        float s = b2[0];
        #pragma unroll 8
        for (int k = 0; k < NK; ++k) {
            const float2 cv = contrib[k];
            if (__float_as_int(cv.y) == tid) s += cv.x;
        }
        const float t = 1.f / (1.f + expf(-s));
        #pragma unroll
        for (int c = 0; c < NC; ++c) acc[c] += t * wf[c * HW + tid];
    }

    // ---- block-reduce the 10 class sums across 8 waves ----
    #pragma unroll
    for (int c = 0; c < NC; ++c) {
        #pragma unroll
        for (int off = 32; off >= 1; off >>= 1)
            acc[c] += __shfl_down(acc[c], off);
    }
    if (lane == 0) {
        #pragma unroll
        for (int c = 0; c < NC; ++c) wsum[wave][c] = acc[c];
    }
    __syncthreads();
    if (tid < NC) {
        float s = bf[tid];
        #pragma unroll
        for (int w = 0; w < NWAVE; ++w) s += wsum[w][tid];
        out[b * NC + tid] = 1.f / (1.f + expf(-s));
    }
}

extern "C" void kernel_launch(void* const* d_in, const int* in_sizes, int n_in,
                              void* d_out, int out_size, void* d_ws, size_t ws_size,
                              hipStream_t stream) {
    const float* x        = (const float*)d_in[0];
    const float* patterns = (const float*)d_in[1];
    const float* w2       = (const float*)d_in[2];
    const float* b2       = (const float*)d_in[3];
    const float* wf       = (const float*)d_in[4];
    const float* bf       = (const float*)d_in[5];
    float* out = (float*)d_out;

    geneo_mlp_kernel<<<NB, 512, 0, stream>>>(x, patterns, w2, b2, wf, bf, out);
}

// Round 5
// 23.801 us; speedup vs baseline: 2.5358x; 1.0037x over previous
//
#include <hip/hip_runtime.h>
#include <math.h>

#define NB 512
#define NK 64
#define NP 25
#define HW 400
#define NC 10
#define NWAVE 8

__global__ __launch_bounds__(512, 4) void geneo_mlp_kernel(
    const float* __restrict__ x,        // (B,1,20,20)
    const float* __restrict__ patterns, // (K,1,5,5)
    const float* __restrict__ w2,       // (1,K)
    const float* __restrict__ b2,       // (1,)
    const float* __restrict__ wf,       // (NC,400)
    const float* __restrict__ bf,       // (NC,)
    float* __restrict__ out)            // (B,NC)
{
    // 4 pre-shifted copies of the padded 24x24 image: copy j holds
    // padded col (w + j) at index w, so strip cs reads 16B-aligned at
    // base col cs*4 of copy cs (orig padded cols cs*5 .. cs*5+8).
    __shared__ __align__(16) float xps[4][24 * 24];
    __shared__ __align__(16) float pat_lds[NK * NP];
    __shared__ float  redv[NWAVE][NK];
    __shared__ int    redi[NWAVE][NK];
    __shared__ float2 contrib[NK];      // (F*w2, bitcast idx)
    __shared__ float  wsum[NWAVE][NC];

    const int tid  = threadIdx.x;
    const int b    = blockIdx.x;
    const int lane = tid & 63;
    const int wave = tid >> 6;
    const int rw   = wave >> 2;   // row half:  rows rw*10 .. rw*10+9
    const int cs   = wave & 3;    // col strip: cols cs*5 .. cs*5+4

    // ---- stage 4 shifted padded copies (pad=2; outside -> 0) ----
    #pragma unroll
    for (int cp = 0; cp < 4; ++cp) {
        for (int i = tid; i < 576; i += 512) {
            const int ph = i / 24;            // padded row
            const int w0 = i - ph * 24;       // index within copy
            const int pc = w0 + cp;           // original padded col
            float v = 0.f;
            if (ph >= 2 && ph < 22 && pc >= 2 && pc < 22)
                v = x[b * HW + (ph - 2) * 20 + (pc - 2)];
            xps[cp][i] = v;
        }
    }
    // ---- stage patterns coalesced (1600 floats = 400 float4) ----
    if (tid < 400)
        reinterpret_cast<float4*>(pat_lds)[tid] =
            reinterpret_cast<const float4*>(patterns)[tid];
    __syncthreads();

    // ---- lane owns pattern k = lane: 25 values in registers ----
    // stride-25 b32 reads: lane*25 mod 32 distinct per 32 lanes -> 2-way (free)
    float patv[NP];
    #pragma unroll
    for (int j = 0; j < NP; ++j) patv[j] = pat_lds[lane * NP + j];

    // ---- strip: 10 rows x 5 cols, all 64 k in parallel (lane = k) ----
    const float* xbase = &xps[cs][cs * 4];   // row r at xbase + r*24, cols 0..8 used
    const int H0   = rw * 10;
    const int col0 = cs * 5;

    float smin = 1e30f;
    int   bi   = 0;
    float Wf[5][9];                          // 45 VGPRs, static-indexed only

    // initial fill: padded rows H0..H0+4 -> slots 0..4
    #pragma unroll
    for (int q = 0; q < 5; ++q) {
        const float* rp = xbase + (H0 + q) * 24;
        const float4 a = *reinterpret_cast<const float4*>(rp);
        const float4 c = *reinterpret_cast<const float4*>(rp + 4);
        Wf[q][0] = a.x; Wf[q][1] = a.y; Wf[q][2] = a.z; Wf[q][3] = a.w;
        Wf[q][4] = c.x; Wf[q][5] = c.y; Wf[q][6] = c.z; Wf[q][7] = c.w;
        Wf[q][8] = rp[8];
    }

    #pragma unroll 1
    for (int rr = 0; rr < 2; ++rr) {
        #pragma unroll
        for (int p = 0; p < 5; ++p) {        // phase: slot indices static
            const int i = rr * 5 + p;        // step 0..9
            const int h = H0 + i;            // output row
            #pragma unroll
            for (int px = 0; px < 5; ++px) {
                float s = 0.f;
                #pragma unroll
                for (int dy = 0; dy < 5; ++dy) {
                    const int slot = (p + dy) % 5;   // compile-time
                    #pragma unroll
                    for (int dx = 0; dx < 5; ++dx)
                        s += fabsf(patv[dy * 5 + dx] - Wf[slot][px + dx]);
                }
                const int pix = h * 20 + col0 + px;
                if (s < smin) { smin = s; bi = pix; }   // strict <: first occ.
            }
            // retire slot p, load padded row h+5 (exists while step < 9)
            if (rr * 5 + p < 9) {
                const float* rp = xbase + (h + 5) * 24;
                const float4 a = *reinterpret_cast<const float4*>(rp);
                const float4 c = *reinterpret_cast<const float4*>(rp + 4);
                Wf[p][0] = a.x; Wf[p][1] = a.y; Wf[p][2] = a.z; Wf[p][3] = a.w;
                Wf[p][4] = c.x; Wf[p][5] = c.y; Wf[p][6] = c.z; Wf[p][7] = c.w;
                Wf[p][8] = rp[8];
            }
        }
    }
    redv[wave][lane] = smin;
    redi[wave][lane] = bi;
    __syncthreads();

    // ---- combine 8 wave partials per k, lexicographic (s, idx) min ----
    if (tid < NK) {
        float v0 = redv[0][tid];
        int   i0 = redi[0][tid];
        #pragma unroll
        for (int w = 1; w < NWAVE; ++w) {
            const float ov = redv[w][tid];
            const int   oi = redi[w][tid];
            if (ov < v0 || (ov == v0 && oi < i0)) { v0 = ov; i0 = oi; }
        }
        const float F = 1.f - v0 * (1.f / 25.f);
        contrib[tid] = make_float2(F * w2[tid], __int_as_float(i0));
    }
    __syncthreads();

    // ---- sigmoid(scatter + b2) at owned pixel; partial 400->10 dot ----
    float acc[NC];
    #pragma unroll
    for (int c = 0; c < NC; ++c) acc[c] = 0.f;

    if (tid < HW) {
        float s = b2[0];
        #pragma unroll 8
        for (int k = 0; k < NK; ++k) {
            const float2 cv = contrib[k];
            if (__float_as_int(cv.y) == tid) s += cv.x;
        }
        const float t = 1.f / (1.f + expf(-s));
        #pragma unroll
        for (int c = 0; c < NC; ++c) acc[c] += t * wf[c * HW + tid];
    }

    // ---- block-reduce the 10 class sums across 8 waves ----
    #pragma unroll
    for (int c = 0; c < NC; ++c) {
        #pragma unroll
        for (int off = 32; off >= 1; off >>= 1)
            acc[c] += __shfl_down(acc[c], off);
    }
    if (lane == 0) {
        #pragma unroll
        for (int c = 0; c < NC; ++c) wsum[wave][c] = acc[c];
    }
    __syncthreads();
    if (tid < NC) {
        float s = bf[tid];
        #pragma unroll
        for (int w = 0; w < NWAVE; ++w) s += wsum[w][tid];
        out[b * NC + tid] = 1.f / (1.f + expf(-s));
    }
}

extern "C" void kernel_launch(void* const* d_in, const int* in_sizes, int n_in,
                              void* d_out, int out_size, void* d_ws, size_t ws_size,
                              hipStream_t stream) {
    const float* x        = (const float*)d_in[0];
    const float* patterns = (const float*)d_in[1];
    const float* w2       = (const float*)d_in[2];
    const float* b2       = (const float*)d_in[3];
    const float* wf       = (const float*)d_in[4];
    const float* bf       = (const float*)d_in[5];
    float* out = (float*)d_out;

    geneo_mlp_kernel<<<NB, 512, 0, stream>>>(x, patterns, w2, b2, wf, bf, out);
}